// Round 7
// baseline (691.314 us; speedup 1.0000x reference)
//
#include <hip/hip_runtime.h>

typedef __bf16 bf16_t;
typedef __bf16 bf16x8 __attribute__((ext_vector_type(8)));
typedef __bf16 bf16x4 __attribute__((ext_vector_type(4)));
typedef __bf16 bf16x2 __attribute__((ext_vector_type(2)));
typedef float  f32x4  __attribute__((ext_vector_type(4)));

#define MFMA16(a, b, c) __builtin_amdgcn_mfma_f32_16x16x32_bf16((a), (b), (c), 0, 0, 0)

// ---------------------------------------------------------------------------
// Weight prep: W [Kact,128] f32 row-major -> bf16 MFMA-B-fragment-sequential.
// ---------------------------------------------------------------------------
__global__ void prep_w_kernel(const float* __restrict__ W, bf16_t* __restrict__ Ws,
                              int Kact, int KP) {
    int idx = blockIdx.x * 256 + threadIdx.x;
    if (idx >= 128 * KP) return;
    int j    = idx & 7;
    int lane = (idx >> 3) & 63;
    int ct   = (idx >> 9) & 7;
    int kc   = idx >> 12;
    int n = ct * 16 + (lane & 15);
    int k = kc * 32 + (lane >> 4) * 8 + j;
    Ws[idx] = (bf16_t)((k < Kact) ? W[k * 128 + n] : 0.0f);
}

// ---------------------------------------------------------------------------
// CSR build: histogram -> 3-phase scan -> scatter perm (eorig = inverse).
// ---------------------------------------------------------------------------
__global__ __launch_bounds__(256) void hist_kernel(const int* __restrict__ ei,
                                                   int* __restrict__ deg, int E) {
    int t = blockIdx.x * 256 + threadIdx.x;
    if (t < E) atomicAdd(&deg[ei[(long)E + t]], 1);
}

__global__ __launch_bounds__(256) void scanA_kernel(const int* __restrict__ deg,
                                                    int* __restrict__ partials,
                                                    int* __restrict__ bsums, int N) {
    __shared__ int s[256];
    int b = blockIdx.x, t = threadIdx.x;
    int base = b * 1024 + t * 4;
    int v0 = (base + 0 < N) ? deg[base + 0] : 0;
    int v1 = (base + 1 < N) ? deg[base + 1] : 0;
    int v2 = (base + 2 < N) ? deg[base + 2] : 0;
    int v3 = (base + 3 < N) ? deg[base + 3] : 0;
    int local = v0 + v1 + v2 + v3;
    s[t] = local;
    __syncthreads();
    for (int off = 1; off < 256; off <<= 1) {
        int v = (t >= off) ? s[t - off] : 0;
        __syncthreads();
        s[t] += v;
        __syncthreads();
    }
    int excl = s[t] - local;
    if (base + 0 < N) partials[base + 0] = excl;
    if (base + 1 < N) partials[base + 1] = excl + v0;
    if (base + 2 < N) partials[base + 2] = excl + v0 + v1;
    if (base + 3 < N) partials[base + 3] = excl + v0 + v1 + v2;
    if (t == 255) bsums[b] = s[255];
}

__global__ __launch_bounds__(256) void scanB_kernel(const int* __restrict__ bsums,
                                                    int* __restrict__ boff,
                                                    int* __restrict__ rowptr,
                                                    int NB, int N) {
    __shared__ int s[256];
    int t = threadIdx.x;
    int local = (t < NB) ? bsums[t] : 0;
    s[t] = local;
    __syncthreads();
    for (int off = 1; off < 256; off <<= 1) {
        int v = (t >= off) ? s[t - off] : 0;
        __syncthreads();
        s[t] += v;
        __syncthreads();
    }
    if (t < NB) boff[t] = s[t] - local;
    if (t == NB - 1) rowptr[N] = s[t];
}

__global__ __launch_bounds__(256) void scanC_kernel(const int* __restrict__ partials,
                                                    const int* __restrict__ boff,
                                                    int* __restrict__ rowptr,
                                                    int* __restrict__ cursor, int N) {
    int i = blockIdx.x * 256 + threadIdx.x;
    if (i >= N) return;
    int v = partials[i] + boff[i >> 10];
    rowptr[i] = v;
    cursor[i] = v;
}

__global__ __launch_bounds__(256) void scatter_kernel(const int* __restrict__ ei,
                                                      int* __restrict__ cursor,
                                                      int* __restrict__ srcp,
                                                      int* __restrict__ eorig, int E) {
    int t = blockIdx.x * 256 + threadIdx.x;
    if (t >= E) return;
    int d = ei[(long)E + t];
    int pos = atomicAdd(&cursor[d], 1);
    srcp[pos] = ei[t];
    eorig[pos] = t;
}

// ---------------------------------------------------------------------------
// Node encoder: h = x[M,32] @ W + bias, out bf16, LDS-roundtrip coalesced.
// ---------------------------------------------------------------------------
__global__ __launch_bounds__(256) void node_enc_kernel(
    const float* __restrict__ A, int M,
    const bf16_t* __restrict__ Ws, const float* __restrict__ bias,
    bf16_t* __restrict__ outp)
{
    constexpr int S = 136;
    __shared__ bf16_t T[128 * S];
    __shared__ float  bls[128];

    const int  tid  = threadIdx.x;
    const long row0 = (long)blockIdx.x * 128;

    if (tid < 128) bls[tid] = bias[tid];

    for (int i = tid; i < 128 * 8; i += 256) {
        int r = i / 8, c4 = (i % 8) * 4;
        long gr = row0 + r;
        float4 v = make_float4(0.f, 0.f, 0.f, 0.f);
        if (gr < M) v = *(const float4*)(A + gr * 32 + c4);
        bf16_t* d = &T[r * S + c4];
        d[0] = (bf16_t)v.x; d[1] = (bf16_t)v.y; d[2] = (bf16_t)v.z; d[3] = (bf16_t)v.w;
    }
    __syncthreads();

    const int wv = tid >> 6, lane = tid & 63;
    const int l16 = lane & 15, quad = lane >> 4;

    f32x4 acc[2][8];
#pragma unroll
    for (int r = 0; r < 2; r++)
#pragma unroll
        for (int c = 0; c < 8; c++) acc[r][c] = (f32x4){0.f, 0.f, 0.f, 0.f};

    {
        bf16x8 af0 = *(const bf16x8*)&T[(wv * 32 + l16) * S + quad * 8];
        bf16x8 af1 = *(const bf16x8*)&T[(wv * 32 + 16 + l16) * S + quad * 8];
#pragma unroll
        for (int c = 0; c < 8; c++) {
            bf16x8 bfr = *(const bf16x8*)&Ws[((c * 64) + lane) * 8];
            acc[0][c] = MFMA16(af0, bfr, acc[0][c]);
            acc[1][c] = MFMA16(af1, bfr, acc[1][c]);
        }
    }
    __syncthreads();

#pragma unroll
    for (int r = 0; r < 2; r++) {
        int mrow = wv * 32 + r * 16 + quad * 4;
#pragma unroll
        for (int c = 0; c < 8; c++) {
            int col = c * 16 + l16;
            float bb = bls[col];
#pragma unroll
            for (int q = 0; q < 4; q++)
                T[(mrow + q) * S + col] = (bf16_t)(acc[r][c][q] + bb);
        }
    }
    __syncthreads();

    for (int i = tid; i < 128 * 16; i += 256) {
        int row = i >> 4, seg = i & 15;
        long grow = row0 + row;
        if (grow < M)
            *(uint4*)&outp[grow * 128 + seg * 8] = *(const uint4*)&T[row * S + seg * 8];
    }
}

// ---------------------------------------------------------------------------
// Fused edge encoder, 64-row tiles (17.4 KB LDS -> ~6 blocks/CU):
// CSR-order compute, gather-in via eorig, sequential write.
// ---------------------------------------------------------------------------
__global__ __launch_bounds__(256) void edge_mlp_kernel(
    const float* __restrict__ A, int M,
    const bf16_t* __restrict__ Ws1, const float* __restrict__ b1,
    const bf16_t* __restrict__ Ws2, const float* __restrict__ b2,
    const int* __restrict__ eorig, bf16_t* __restrict__ outp)
{
    constexpr int S = 136;
    __shared__ bf16_t T[64 * S];
    __shared__ float  bls1[128], bls2[128];
    __shared__ int    eors[64];

    const int  tid  = threadIdx.x;
    const long row0 = (long)blockIdx.x * 64;

    if (tid < 128) { bls1[tid] = b1[tid]; bls2[tid] = b2[tid]; }
    if (tid < 64) eors[tid] = (row0 + tid < M) ? eorig[row0 + tid] : 0;
    __syncthreads();

    // gather 64 rows x 16 f32 (pad cols 16..31 with zeros)
    for (int i = tid; i < 64 * 8; i += 256) {
        int r = i / 8, c4 = (i % 8) * 4;
        float4 v = make_float4(0.f, 0.f, 0.f, 0.f);
        if (row0 + r < M && c4 < 16) v = *(const float4*)(A + (long)eors[r] * 16 + c4);
        bf16_t* d = &T[r * S + c4];
        d[0] = (bf16_t)v.x; d[1] = (bf16_t)v.y; d[2] = (bf16_t)v.z; d[3] = (bf16_t)v.w;
    }
    __syncthreads();

    const int wv = tid >> 6, lane = tid & 63;
    const int l16 = lane & 15, quad = lane >> 4;
    const int mbase = wv * 16 + quad * 4;

    f32x4 acc[8];
#pragma unroll
    for (int c = 0; c < 8; c++) acc[c] = (f32x4){0.f, 0.f, 0.f, 0.f};

    {   // stage 1: K=32
        bf16x8 af = *(const bf16x8*)&T[(wv * 16 + l16) * S + quad * 8];
#pragma unroll
        for (int c = 0; c < 8; c++) {
            bf16x8 bfr = *(const bf16x8*)&Ws1[((c * 64) + lane) * 8];
            acc[c] = MFMA16(af, bfr, acc[c]);
        }
    }
    __syncthreads();   // T becomes H

#pragma unroll
    for (int c = 0; c < 8; c++) {
        int col = c * 16 + l16;
        float bb = bls1[col];
#pragma unroll
        for (int q = 0; q < 4; q++)
            T[(mbase + q) * S + col] = (bf16_t)fmaxf(acc[c][q] + bb, 0.f);
    }
    __syncthreads();

#pragma unroll
    for (int c = 0; c < 8; c++) acc[c] = (f32x4){0.f, 0.f, 0.f, 0.f};

#pragma unroll
    for (int kc = 0; kc < 4; ++kc) {   // stage 2: K=128
        bf16x8 af = *(const bf16x8*)&T[(wv * 16 + l16) * S + kc * 32 + quad * 8];
#pragma unroll
        for (int c = 0; c < 8; c++) {
            bf16x8 bfr = *(const bf16x8*)&Ws2[(((kc * 8 + c) * 64) + lane) * 8];
            acc[c] = MFMA16(af, bfr, acc[c]);
        }
    }
    __syncthreads();   // T becomes Z

#pragma unroll
    for (int c = 0; c < 8; c++) {
        int col = c * 16 + l16;
        float bb = bls2[col];
#pragma unroll
        for (int q = 0; q < 4; q++)
            T[(mbase + q) * S + col] = (bf16_t)(acc[c][q] + bb);
    }
    __syncthreads();

    for (int i = tid; i < 64 * 16; i += 256) {
        int row = i >> 4, seg = i & 15;
        long grow = row0 + row;
        if (grow < M)
            *(uint4*)&outp[grow * 128 + seg * 8] = *(const uint4*)&T[row * S + seg * 8];
    }
}

// ---------------------------------------------------------------------------
// FUSED aggregation + GINEConv MLP, 64-node tiles:
//   A-tile[r] = h[n] + sum_{CSR(n)} relu(h[src]+e)   (gathered into LDS)
//   z = (relu(A @ W1 + b1)) @ W2 + b2  (bf16 out) + BN sums.
// One wave aggregates 16 nodes (64 lanes x 2 ch); no aggr round-trip.
// ---------------------------------------------------------------------------
__global__ __launch_bounds__(256) void aggr_conv_kernel(
    const bf16_t* __restrict__ h, const bf16_t* __restrict__ e,
    const int* __restrict__ rowptr, const int* __restrict__ srcp, int M,
    const bf16_t* __restrict__ Ws1, const float* __restrict__ b1,
    const bf16_t* __restrict__ Ws2, const float* __restrict__ b2,
    bf16_t* __restrict__ zout, float* __restrict__ bn_sums)
{
    constexpr int S = 136;
    __shared__ bf16_t T[64 * S];
    __shared__ float  bls1[128], bls2[128], bsum[128], bsq[128];

    const int  tid  = threadIdx.x;
    const int  wv   = tid >> 6, lane = tid & 63;
    const long row0 = (long)blockIdx.x * 64;

    if (tid < 128) { bls1[tid] = b1[tid]; bls2[tid] = b2[tid]; bsum[tid] = 0.f; bsq[tid] = 0.f; }

    // --- gather + aggregate into LDS A-tile: wave wv -> nodes wv*16..+15 ---
    for (int r = wv * 16; r < wv * 16 + 16; ++r) {
        long n = row0 + r;
        float ax = 0.f, ay = 0.f;
        if (n < M) {
            bf16x2 hv = *(const bf16x2*)(h + n * 128 + lane * 2);
            ax = (float)hv[0]; ay = (float)hv[1];     // self term (eps=0)
            int beg = rowptr[n], end = rowptr[n + 1];
            int i = beg;
            for (; i + 3 < end; i += 4) {
                int s0 = srcp[i], s1 = srcp[i + 1], s2 = srcp[i + 2], s3 = srcp[i + 3];
                bf16x2 h0 = *(const bf16x2*)(h + (long)s0 * 128 + lane * 2);
                bf16x2 h1 = *(const bf16x2*)(h + (long)s1 * 128 + lane * 2);
                bf16x2 h2 = *(const bf16x2*)(h + (long)s2 * 128 + lane * 2);
                bf16x2 h3 = *(const bf16x2*)(h + (long)s3 * 128 + lane * 2);
                bf16x2 e0 = *(const bf16x2*)(e + (long)(i + 0) * 128 + lane * 2);
                bf16x2 e1 = *(const bf16x2*)(e + (long)(i + 1) * 128 + lane * 2);
                bf16x2 e2 = *(const bf16x2*)(e + (long)(i + 2) * 128 + lane * 2);
                bf16x2 e3 = *(const bf16x2*)(e + (long)(i + 3) * 128 + lane * 2);
                ax += fmaxf((float)h0[0] + (float)e0[0], 0.f);
                ay += fmaxf((float)h0[1] + (float)e0[1], 0.f);
                ax += fmaxf((float)h1[0] + (float)e1[0], 0.f);
                ay += fmaxf((float)h1[1] + (float)e1[1], 0.f);
                ax += fmaxf((float)h2[0] + (float)e2[0], 0.f);
                ay += fmaxf((float)h2[1] + (float)e2[1], 0.f);
                ax += fmaxf((float)h3[0] + (float)e3[0], 0.f);
                ay += fmaxf((float)h3[1] + (float)e3[1], 0.f);
            }
            for (; i < end; ++i) {
                int s0 = srcp[i];
                bf16x2 h0 = *(const bf16x2*)(h + (long)s0 * 128 + lane * 2);
                bf16x2 e0 = *(const bf16x2*)(e + (long)i * 128 + lane * 2);
                ax += fmaxf((float)h0[0] + (float)e0[0], 0.f);
                ay += fmaxf((float)h0[1] + (float)e0[1], 0.f);
            }
        }
        bf16x2 o; o[0] = (bf16_t)ax; o[1] = (bf16_t)ay;
        *(bf16x2*)&T[r * S + lane * 2] = o;
    }
    __syncthreads();

    const int l16 = lane & 15, quad = lane >> 4;
    const int mbase = wv * 16 + quad * 4;

    f32x4 acc[8];
#pragma unroll
    for (int c = 0; c < 8; c++) acc[c] = (f32x4){0.f, 0.f, 0.f, 0.f};

#pragma unroll
    for (int kc = 0; kc < 4; ++kc) {
        bf16x8 af = *(const bf16x8*)&T[(wv * 16 + l16) * S + kc * 32 + quad * 8];
#pragma unroll
        for (int c = 0; c < 8; c++) {
            bf16x8 bfr = *(const bf16x8*)&Ws1[(((kc * 8 + c) * 64) + lane) * 8];
            acc[c] = MFMA16(af, bfr, acc[c]);
        }
    }
    __syncthreads();   // T becomes H

#pragma unroll
    for (int c = 0; c < 8; c++) {
        int col = c * 16 + l16;
        float bb = bls1[col];
#pragma unroll
        for (int q = 0; q < 4; q++)
            T[(mbase + q) * S + col] = (bf16_t)fmaxf(acc[c][q] + bb, 0.f);
    }
    __syncthreads();

#pragma unroll
    for (int c = 0; c < 8; c++) acc[c] = (f32x4){0.f, 0.f, 0.f, 0.f};

#pragma unroll
    for (int kc = 0; kc < 4; ++kc) {
        bf16x8 af = *(const bf16x8*)&T[(wv * 16 + l16) * S + kc * 32 + quad * 8];
#pragma unroll
        for (int c = 0; c < 8; c++) {
            bf16x8 bfr = *(const bf16x8*)&Ws2[(((kc * 8 + c) * 64) + lane) * 8];
            acc[c] = MFMA16(af, bfr, acc[c]);
        }
    }
    __syncthreads();   // T becomes Z

#pragma unroll
    for (int c = 0; c < 8; c++) {
        int col = c * 16 + l16;
        float bb = bls2[col];
        float s = 0.f, s2 = 0.f;
#pragma unroll
        for (int q = 0; q < 4; q++) {
            float v = acc[c][q] + bb;
            T[(mbase + q) * S + col] = (bf16_t)v;
            if (row0 + mbase + q < M) { s += v; s2 += v * v; }
        }
        s  += __shfl_xor(s, 16);  s  += __shfl_xor(s, 32);
        s2 += __shfl_xor(s2, 16); s2 += __shfl_xor(s2, 32);
        if (quad == 0) { atomicAdd(&bsum[col], s); atomicAdd(&bsq[col], s2); }
    }
    __syncthreads();

    for (int i = tid; i < 64 * 16; i += 256) {
        int row = i >> 4, seg = i & 15;
        long grow = row0 + row;
        if (grow < M)
            *(uint4*)&zout[grow * 128 + seg * 8] = *(const uint4*)&T[row * S + seg * 8];
    }
    if (tid < 128) {
        atomicAdd(&bn_sums[tid], bsum[tid]);
        atomicAdd(&bn_sums[128 + tid], bsq[tid]);
    }
}

// ---------------------------------------------------------------------------
__global__ void bn_fin_kernel(float* __restrict__ sums, const float* __restrict__ gamma,
                              const float* __restrict__ beta, float* __restrict__ scsh, int N)
{
    int c = threadIdx.x;
    float s  = sums[c];
    float sq = sums[128 + c];
    float mean = s / (float)N;
    float var  = sq / (float)N - mean * mean;
    float inv  = rsqrtf(var + 1e-5f);
    float sc   = gamma[c] * inv;
    scsh[c]       = sc;
    scsh[128 + c] = beta[c] - mean * sc;
    sums[c] = 0.f;
    sums[128 + c] = 0.f;
}

__global__ __launch_bounds__(256) void bn_apply_kernel(
    const bf16_t* __restrict__ z, const float* __restrict__ scsh,
    bf16_t* __restrict__ h, int total8)
{
    int idx = blockIdx.x * 256 + threadIdx.x;
    if (idx >= total8) return;
    long base = (long)idx * 8;
    int c0 = (int)(base & 127);
    bf16x8 zv = *(const bf16x8*)(z + base);
    bf16x8 hv;
#pragma unroll
    for (int j = 0; j < 8; j++)
        hv[j] = (bf16_t)fmaxf((float)zv[j] * scsh[c0 + j] + scsh[128 + c0 + j], 0.f);
    *(bf16x8*)(h + base) = hv;
}

// ---------------------------------------------------------------------------
__global__ __launch_bounds__(128) void pool_kernel(
    const bf16_t* __restrict__ h, const int* __restrict__ batch,
    float* __restrict__ gsum, float* __restrict__ cnt, int N)
{
    int c = threadIdx.x;
    int n0 = blockIdx.x * 256;
    int n1 = min(n0 + 256, N);
    float acc = 0.f;
    int cur = -1, rc = 0;
    for (int n = n0; n < n1; ++n) {
        int g = batch[n];
        if (g != cur) {
            if (cur >= 0) {
                atomicAdd(&gsum[(long)cur * 128 + c], acc);
                if (c == 0) atomicAdd(&cnt[cur], (float)rc);
            }
            cur = g; acc = 0.f; rc = 0;
        }
        acc += (float)h[(long)n * 128 + c];
        rc++;
    }
    if (cur >= 0) {
        atomicAdd(&gsum[(long)cur * 128 + c], acc);
        if (c == 0) atomicAdd(&cnt[cur], (float)rc);
    }
}

__global__ __launch_bounds__(128) void head_kernel(
    const float* __restrict__ gsum, const float* __restrict__ cnt,
    const float* __restrict__ ext_in,
    const float* __restrict__ ew1, const float* __restrict__ eb1,
    const float* __restrict__ ew2, const float* __restrict__ eb2,
    const float* __restrict__ rw1, const float* __restrict__ rb1,
    const float* __restrict__ rw2, const float* __restrict__ rb2,
    float* __restrict__ out)
{
    int g = blockIdx.x, c = threadIdx.x;
    __shared__ float sx[8];
    __shared__ float h1[128];
    __shared__ float comb[256];
    __shared__ float red[128];

    if (c < 8) sx[c] = ext_in[g * 8 + c];
    __syncthreads();
    float a = eb1[c];
#pragma unroll
    for (int k = 0; k < 8; k++) a += sx[k] * ew1[k * 128 + c];
    h1[c] = fmaxf(a, 0.f);
    __syncthreads();
    float b = eb2[c];
    for (int k = 0; k < 128; k++) b += h1[k] * ew2[k * 128 + c];
    comb[c]       = gsum[(long)g * 128 + c] / fmaxf(cnt[g], 1.0f);
    comb[128 + c] = b;
    __syncthreads();
    float r = rb1[c];
    for (int k = 0; k < 256; k++) r += comb[k] * rw1[k * 128 + c];
    r = fmaxf(r, 0.f);
    red[c] = r * rw2[c];
    __syncthreads();
    if (c == 0) {
        float s = rb2[0];
        for (int k = 0; k < 128; k++) s += red[k];
        out[g] = s;
    }
}

// ---------------------------------------------------------------------------
extern "C" void kernel_launch(void* const* d_in, const int* in_sizes, int n_in,
                              void* d_out, int out_size, void* d_ws, size_t ws_size,
                              hipStream_t stream)
{
    const float* x         = (const float*)d_in[0];
    const float* edge_attr = (const float*)d_in[1];
    const float* externals = (const float*)d_in[2];
    const float* node_w    = (const float*)d_in[3];
    const float* node_b    = (const float*)d_in[4];
    const float* ee_w1     = (const float*)d_in[5];
    const float* ee_b1     = (const float*)d_in[6];
    const float* ee_w2     = (const float*)d_in[7];
    const float* ee_b2     = (const float*)d_in[8];
    const float* conv_w1   = (const float*)d_in[9];
    const float* conv_b1   = (const float*)d_in[10];
    const float* conv_w2   = (const float*)d_in[11];
    const float* conv_b2   = (const float*)d_in[12];
    const float* bn_gamma  = (const float*)d_in[13];
    const float* bn_beta   = (const float*)d_in[14];
    const float* ext_w1    = (const float*)d_in[15];
    const float* ext_b1    = (const float*)d_in[16];
    const float* ext_w2    = (const float*)d_in[17];
    const float* ext_b2    = (const float*)d_in[18];
    const float* reg_w1    = (const float*)d_in[19];
    const float* reg_b1    = (const float*)d_in[20];
    const float* reg_w2    = (const float*)d_in[21];
    const float* reg_b2    = (const float*)d_in[22];
    const int* edge_index  = (const int*)d_in[23];
    const int* batch       = (const int*)d_in[24];

    const int N = in_sizes[0] / 32;
    const int E = in_sizes[1] / 16;
    const int G = in_sizes[2] / 8;
    const int NB = (N + 1023) / 1024;

    char* p = (char*)d_ws;
    auto alloc = [&](size_t bytes) -> void* {
        void* r = (void*)p;
        p += (bytes + 255) & ~(size_t)255;
        return r;
    };
    bf16_t* h       = (bf16_t*)alloc((size_t)N * 128 * 2);
    bf16_t* zbuf    = (bf16_t*)alloc((size_t)N * 128 * 2);
    bf16_t* ebuf    = (bf16_t*)alloc((size_t)E * 128 * 2);   // dst-sorted
    int*    deg     = (int*)alloc((size_t)N * 4);
    int*    rowptr  = (int*)alloc(((size_t)N + 1) * 4);
    int*    cursor  = (int*)alloc((size_t)N * 4);
    int*    partials= (int*)alloc((size_t)N * 4);
    int*    bsums   = (int*)alloc((size_t)NB * 4);
    int*    boff    = (int*)alloc((size_t)NB * 4);
    int*    srcp    = (int*)alloc((size_t)E * 4);
    int*    eorig   = (int*)alloc((size_t)E * 4);
    bf16_t* node_wt = (bf16_t*)alloc(128 * 32 * 2);
    bf16_t* ee_w1t  = (bf16_t*)alloc(128 * 32 * 2);
    bf16_t* ee_w2t  = (bf16_t*)alloc(128 * 128 * 2);
    bf16_t* cw1t    = (bf16_t*)alloc(3 * 128 * 128 * 2);
    bf16_t* cw2t    = (bf16_t*)alloc(3 * 128 * 128 * 2);
    float*  bn_sums = (float*)alloc(256 * 4);
    float*  scsh    = (float*)alloc(256 * 4);
    float*  gsum    = (float*)alloc((size_t)G * 128 * 4);
    float*  cnt     = (float*)alloc((size_t)G * 4);

    // --- CSR build (by dst) ---
    hipMemsetAsync(deg, 0, (size_t)N * 4, stream);
    hipMemsetAsync(bn_sums, 0, 256 * 4, stream);
    hist_kernel<<<(E + 255) / 256, 256, 0, stream>>>(edge_index, deg, E);
    scanA_kernel<<<NB, 256, 0, stream>>>(deg, partials, bsums, N);
    scanB_kernel<<<1, 256, 0, stream>>>(bsums, boff, rowptr, NB, N);
    scanC_kernel<<<(N + 255) / 256, 256, 0, stream>>>(partials, boff, rowptr, cursor, N);
    scatter_kernel<<<(E + 255) / 256, 256, 0, stream>>>(edge_index, cursor, srcp, eorig, E);

    // --- weight prep ---
    prep_w_kernel<<<16, 256, 0, stream>>>(node_w, node_wt, 32, 32);
    prep_w_kernel<<<16, 256, 0, stream>>>(ee_w1, ee_w1t, 16, 32);
    prep_w_kernel<<<64, 256, 0, stream>>>(ee_w2, ee_w2t, 128, 128);
    for (int l = 0; l < 3; l++) {
        prep_w_kernel<<<64, 256, 0, stream>>>(conv_w1 + l * 16384, cw1t + l * 16384, 128, 128);
        prep_w_kernel<<<64, 256, 0, stream>>>(conv_w2 + l * 16384, cw2t + l * 16384, 128, 128);
    }

    // --- node encoder ---
    node_enc_kernel<<<(N + 127) / 128, 256, 0, stream>>>(x, N, node_wt, node_b, h);

    // --- edge encoder, CSR-order compute, sequential write ---
    edge_mlp_kernel<<<(E + 63) / 64, 256, 0, stream>>>(
        edge_attr, E, ee_w1t, ee_b1, ee_w2t, ee_b2, eorig, ebuf);

    // --- GINE layers: fused gather+conv, then BN ---
    const int total8 = N * 128 / 8;
    for (int l = 0; l < 3; l++) {
        aggr_conv_kernel<<<(N + 63) / 64, 256, 0, stream>>>(
            h, ebuf, rowptr, srcp, N,
            cw1t + l * 16384, conv_b1 + l * 128,
            cw2t + l * 16384, conv_b2 + l * 128, zbuf, bn_sums);
        bn_fin_kernel<<<1, 128, 0, stream>>>(bn_sums, bn_gamma + l * 128, bn_beta + l * 128, scsh, N);
        bn_apply_kernel<<<(total8 + 255) / 256, 256, 0, stream>>>(zbuf, scsh, h, total8);
    }

    // --- pooling + head ---
    hipMemsetAsync(gsum, 0, (size_t)G * 128 * 4, stream);
    hipMemsetAsync(cnt, 0, (size_t)G * 4, stream);
    pool_kernel<<<(N + 255) / 256, 128, 0, stream>>>(h, batch, gsum, cnt, N);
    head_kernel<<<G, 128, 0, stream>>>(gsum, cnt, externals,
                                       ext_w1, ext_b1, ext_w2, ext_b2,
                                       reg_w1, reg_b1, reg_w2, reg_b2,
                                       (float*)d_out);
}

// Round 8
// 647.524 us; speedup vs baseline: 1.0676x; 1.0676x over previous
//
#include <hip/hip_runtime.h>

typedef __bf16 bf16_t;
typedef __bf16 bf16x8 __attribute__((ext_vector_type(8)));
typedef __bf16 bf16x4 __attribute__((ext_vector_type(4)));
typedef __bf16 bf16x2 __attribute__((ext_vector_type(2)));
typedef float  f32x4  __attribute__((ext_vector_type(4)));

#define MFMA16(a, b, c) __builtin_amdgcn_mfma_f32_16x16x32_bf16((a), (b), (c), 0, 0, 0)

// ---------------------------------------------------------------------------
// Weight prep: W [Kact,128] f32 row-major -> bf16 MFMA-B-fragment-sequential.
// ---------------------------------------------------------------------------
__global__ void prep_w_kernel(const float* __restrict__ W, bf16_t* __restrict__ Ws,
                              int Kact, int KP) {
    int idx = blockIdx.x * 256 + threadIdx.x;
    if (idx >= 128 * KP) return;
    int j    = idx & 7;
    int lane = (idx >> 3) & 63;
    int ct   = (idx >> 9) & 7;
    int kc   = idx >> 12;
    int n = ct * 16 + (lane & 15);
    int k = kc * 32 + (lane >> 4) * 8 + j;
    Ws[idx] = (bf16_t)((k < Kact) ? W[k * 128 + n] : 0.0f);
}

// ---------------------------------------------------------------------------
// CSR build: histogram -> 3-phase scan -> scatter perm (eorig = inverse).
// ---------------------------------------------------------------------------
__global__ __launch_bounds__(256) void hist_kernel(const int* __restrict__ ei,
                                                   int* __restrict__ deg, int E) {
    int t = blockIdx.x * 256 + threadIdx.x;
    if (t < E) atomicAdd(&deg[ei[(long)E + t]], 1);
}

__global__ __launch_bounds__(256) void scanA_kernel(const int* __restrict__ deg,
                                                    int* __restrict__ partials,
                                                    int* __restrict__ bsums, int N) {
    __shared__ int s[256];
    int b = blockIdx.x, t = threadIdx.x;
    int base = b * 1024 + t * 4;
    int v0 = (base + 0 < N) ? deg[base + 0] : 0;
    int v1 = (base + 1 < N) ? deg[base + 1] : 0;
    int v2 = (base + 2 < N) ? deg[base + 2] : 0;
    int v3 = (base + 3 < N) ? deg[base + 3] : 0;
    int local = v0 + v1 + v2 + v3;
    s[t] = local;
    __syncthreads();
    for (int off = 1; off < 256; off <<= 1) {
        int v = (t >= off) ? s[t - off] : 0;
        __syncthreads();
        s[t] += v;
        __syncthreads();
    }
    int excl = s[t] - local;
    if (base + 0 < N) partials[base + 0] = excl;
    if (base + 1 < N) partials[base + 1] = excl + v0;
    if (base + 2 < N) partials[base + 2] = excl + v0 + v1;
    if (base + 3 < N) partials[base + 3] = excl + v0 + v1 + v2;
    if (t == 255) bsums[b] = s[255];
}

__global__ __launch_bounds__(256) void scanB_kernel(const int* __restrict__ bsums,
                                                    int* __restrict__ boff,
                                                    int* __restrict__ rowptr,
                                                    int NB, int N) {
    __shared__ int s[256];
    int t = threadIdx.x;
    int local = (t < NB) ? bsums[t] : 0;
    s[t] = local;
    __syncthreads();
    for (int off = 1; off < 256; off <<= 1) {
        int v = (t >= off) ? s[t - off] : 0;
        __syncthreads();
        s[t] += v;
        __syncthreads();
    }
    if (t < NB) boff[t] = s[t] - local;
    if (t == NB - 1) rowptr[N] = s[t];
}

__global__ __launch_bounds__(256) void scanC_kernel(const int* __restrict__ partials,
                                                    const int* __restrict__ boff,
                                                    int* __restrict__ rowptr,
                                                    int* __restrict__ cursor, int N) {
    int i = blockIdx.x * 256 + threadIdx.x;
    if (i >= N) return;
    int v = partials[i] + boff[i >> 10];
    rowptr[i] = v;
    cursor[i] = v;
}

__global__ __launch_bounds__(256) void scatter_kernel(const int* __restrict__ ei,
                                                      int* __restrict__ cursor,
                                                      int* __restrict__ srcp,
                                                      int* __restrict__ eorig, int E) {
    int t = blockIdx.x * 256 + threadIdx.x;
    if (t >= E) return;
    int d = ei[(long)E + t];
    int pos = atomicAdd(&cursor[d], 1);
    srcp[pos] = ei[t];
    eorig[pos] = t;
}

// ---------------------------------------------------------------------------
// Node encoder: h = x[M,32] @ W + bias, out bf16, LDS-roundtrip coalesced.
// ---------------------------------------------------------------------------
__global__ __launch_bounds__(256) void node_enc_kernel(
    const float* __restrict__ A, int M,
    const bf16_t* __restrict__ Ws, const float* __restrict__ bias,
    bf16_t* __restrict__ outp)
{
    constexpr int S = 136;
    __shared__ bf16_t T[128 * S];
    __shared__ float  bls[128];

    const int  tid  = threadIdx.x;
    const long row0 = (long)blockIdx.x * 128;

    if (tid < 128) bls[tid] = bias[tid];

    for (int i = tid; i < 128 * 8; i += 256) {
        int r = i / 8, c4 = (i % 8) * 4;
        long gr = row0 + r;
        float4 v = make_float4(0.f, 0.f, 0.f, 0.f);
        if (gr < M) v = *(const float4*)(A + gr * 32 + c4);
        bf16_t* d = &T[r * S + c4];
        d[0] = (bf16_t)v.x; d[1] = (bf16_t)v.y; d[2] = (bf16_t)v.z; d[3] = (bf16_t)v.w;
    }
    __syncthreads();

    const int wv = tid >> 6, lane = tid & 63;
    const int l16 = lane & 15, quad = lane >> 4;

    f32x4 acc[2][8];
#pragma unroll
    for (int r = 0; r < 2; r++)
#pragma unroll
        for (int c = 0; c < 8; c++) acc[r][c] = (f32x4){0.f, 0.f, 0.f, 0.f};

    {
        bf16x8 af0 = *(const bf16x8*)&T[(wv * 32 + l16) * S + quad * 8];
        bf16x8 af1 = *(const bf16x8*)&T[(wv * 32 + 16 + l16) * S + quad * 8];
#pragma unroll
        for (int c = 0; c < 8; c++) {
            bf16x8 bfr = *(const bf16x8*)&Ws[((c * 64) + lane) * 8];
            acc[0][c] = MFMA16(af0, bfr, acc[0][c]);
            acc[1][c] = MFMA16(af1, bfr, acc[1][c]);
        }
    }
    __syncthreads();

#pragma unroll
    for (int r = 0; r < 2; r++) {
        int mrow = wv * 32 + r * 16 + quad * 4;
#pragma unroll
        for (int c = 0; c < 8; c++) {
            int col = c * 16 + l16;
            float bb = bls[col];
#pragma unroll
            for (int q = 0; q < 4; q++)
                T[(mrow + q) * S + col] = (bf16_t)(acc[r][c][q] + bb);
        }
    }
    __syncthreads();

    for (int i = tid; i < 128 * 16; i += 256) {
        int row = i >> 4, seg = i & 15;
        long grow = row0 + row;
        if (grow < M)
            *(uint4*)&outp[grow * 128 + seg * 8] = *(const uint4*)&T[row * S + seg * 8];
    }
}

// ---------------------------------------------------------------------------
// Fused edge encoder, 64-row tiles: CSR-order compute, gather-in via eorig,
// sequential write.
// ---------------------------------------------------------------------------
__global__ __launch_bounds__(256) void edge_mlp_kernel(
    const float* __restrict__ A, int M,
    const bf16_t* __restrict__ Ws1, const float* __restrict__ b1,
    const bf16_t* __restrict__ Ws2, const float* __restrict__ b2,
    const int* __restrict__ eorig, bf16_t* __restrict__ outp)
{
    constexpr int S = 136;
    __shared__ bf16_t T[64 * S];
    __shared__ float  bls1[128], bls2[128];
    __shared__ int    eors[64];

    const int  tid  = threadIdx.x;
    const long row0 = (long)blockIdx.x * 64;

    if (tid < 128) { bls1[tid] = b1[tid]; bls2[tid] = b2[tid]; }
    if (tid < 64) eors[tid] = (row0 + tid < M) ? eorig[row0 + tid] : 0;
    __syncthreads();

    for (int i = tid; i < 64 * 8; i += 256) {
        int r = i / 8, c4 = (i % 8) * 4;
        float4 v = make_float4(0.f, 0.f, 0.f, 0.f);
        if (row0 + r < M && c4 < 16) v = *(const float4*)(A + (long)eors[r] * 16 + c4);
        bf16_t* d = &T[r * S + c4];
        d[0] = (bf16_t)v.x; d[1] = (bf16_t)v.y; d[2] = (bf16_t)v.z; d[3] = (bf16_t)v.w;
    }
    __syncthreads();

    const int wv = tid >> 6, lane = tid & 63;
    const int l16 = lane & 15, quad = lane >> 4;
    const int mbase = wv * 16 + quad * 4;

    f32x4 acc[8];
#pragma unroll
    for (int c = 0; c < 8; c++) acc[c] = (f32x4){0.f, 0.f, 0.f, 0.f};

    {   // stage 1: K=32
        bf16x8 af = *(const bf16x8*)&T[(wv * 16 + l16) * S + quad * 8];
#pragma unroll
        for (int c = 0; c < 8; c++) {
            bf16x8 bfr = *(const bf16x8*)&Ws1[((c * 64) + lane) * 8];
            acc[c] = MFMA16(af, bfr, acc[c]);
        }
    }
    __syncthreads();   // T becomes H

#pragma unroll
    for (int c = 0; c < 8; c++) {
        int col = c * 16 + l16;
        float bb = bls1[col];
#pragma unroll
        for (int q = 0; q < 4; q++)
            T[(mbase + q) * S + col] = (bf16_t)fmaxf(acc[c][q] + bb, 0.f);
    }
    __syncthreads();

#pragma unroll
    for (int c = 0; c < 8; c++) acc[c] = (f32x4){0.f, 0.f, 0.f, 0.f};

#pragma unroll
    for (int kc = 0; kc < 4; ++kc) {   // stage 2: K=128
        bf16x8 af = *(const bf16x8*)&T[(wv * 16 + l16) * S + kc * 32 + quad * 8];
#pragma unroll
        for (int c = 0; c < 8; c++) {
            bf16x8 bfr = *(const bf16x8*)&Ws2[(((kc * 8 + c) * 64) + lane) * 8];
            acc[c] = MFMA16(af, bfr, acc[c]);
        }
    }
    __syncthreads();   // T becomes Z

#pragma unroll
    for (int c = 0; c < 8; c++) {
        int col = c * 16 + l16;
        float bb = bls2[col];
#pragma unroll
        for (int q = 0; q < 4; q++)
            T[(mbase + q) * S + col] = (bf16_t)(acc[c][q] + bb);
    }
    __syncthreads();

    for (int i = tid; i < 64 * 16; i += 256) {
        int row = i >> 4, seg = i & 15;
        long grow = row0 + row;
        if (grow < M)
            *(uint4*)&outp[grow * 128 + seg * 8] = *(const uint4*)&T[row * S + seg * 8];
    }
}

// ---------------------------------------------------------------------------
// FUSED BN(+relu) + aggregation + GINEConv MLP, 64-node tiles.
// x-input is pre-BN z (BN=1: hval = relu(z*sc+sh)) or raw h_enc (BN=0).
// srcp is register-broadcast: one coalesced load per 64 edges, __shfl per edge.
// ---------------------------------------------------------------------------
template <int BN>
__global__ __launch_bounds__(256) void aggr_conv_kernel(
    const bf16_t* __restrict__ xin, const float* __restrict__ scsh,
    const bf16_t* __restrict__ e,
    const int* __restrict__ rowptr, const int* __restrict__ srcp, int M,
    const bf16_t* __restrict__ Ws1, const float* __restrict__ b1,
    const bf16_t* __restrict__ Ws2, const float* __restrict__ b2,
    bf16_t* __restrict__ zout, float* __restrict__ bn_sums)
{
    constexpr int S = 136;
    __shared__ bf16_t T[64 * S];
    __shared__ float  bls1[128], bls2[128], bsum[128], bsq[128];

    const int  tid  = threadIdx.x;
    const int  wv   = tid >> 6, lane = tid & 63;
    const long row0 = (long)blockIdx.x * 64;

    if (tid < 128) { bls1[tid] = b1[tid]; bls2[tid] = b2[tid]; bsum[tid] = 0.f; bsq[tid] = 0.f; }

    float sc0 = 1.f, sh0 = 0.f, sc1 = 1.f, sh1 = 0.f;
    if (BN) {
        sc0 = scsh[lane * 2];       sh0 = scsh[128 + lane * 2];
        sc1 = scsh[lane * 2 + 1];   sh1 = scsh[128 + lane * 2 + 1];
    }

    // --- gather + aggregate into LDS A-tile: wave wv -> nodes wv*16..+15 ---
    for (int r = wv * 16; r < wv * 16 + 16; ++r) {
        long n = row0 + r;
        float ax = 0.f, ay = 0.f;
        if (n < M) {
            bf16x2 xv = *(const bf16x2*)(xin + n * 128 + lane * 2);
            ax = BN ? fmaxf((float)xv[0] * sc0 + sh0, 0.f) : (float)xv[0];
            ay = BN ? fmaxf((float)xv[1] * sc1 + sh1, 0.f) : (float)xv[1];
            int beg = rowptr[n], end = rowptr[n + 1];
            for (int base = beg; base < end; base += 64) {
                int cnt = min(64, end - base);
                int sv = (base + lane < end) ? srcp[base + lane] : 0;
                int j = 0;
                for (; j + 3 < cnt; j += 4) {
                    int s0 = __shfl(sv, j), s1 = __shfl(sv, j + 1);
                    int s2 = __shfl(sv, j + 2), s3 = __shfl(sv, j + 3);
                    bf16x2 x0 = *(const bf16x2*)(xin + (long)s0 * 128 + lane * 2);
                    bf16x2 x1 = *(const bf16x2*)(xin + (long)s1 * 128 + lane * 2);
                    bf16x2 x2 = *(const bf16x2*)(xin + (long)s2 * 128 + lane * 2);
                    bf16x2 x3 = *(const bf16x2*)(xin + (long)s3 * 128 + lane * 2);
                    bf16x2 e0 = *(const bf16x2*)(e + (long)(base + j + 0) * 128 + lane * 2);
                    bf16x2 e1 = *(const bf16x2*)(e + (long)(base + j + 1) * 128 + lane * 2);
                    bf16x2 e2 = *(const bf16x2*)(e + (long)(base + j + 2) * 128 + lane * 2);
                    bf16x2 e3 = *(const bf16x2*)(e + (long)(base + j + 3) * 128 + lane * 2);
                    float hx, hy;
                    hx = BN ? fmaxf((float)x0[0] * sc0 + sh0, 0.f) : (float)x0[0];
                    hy = BN ? fmaxf((float)x0[1] * sc1 + sh1, 0.f) : (float)x0[1];
                    ax += fmaxf(hx + (float)e0[0], 0.f);
                    ay += fmaxf(hy + (float)e0[1], 0.f);
                    hx = BN ? fmaxf((float)x1[0] * sc0 + sh0, 0.f) : (float)x1[0];
                    hy = BN ? fmaxf((float)x1[1] * sc1 + sh1, 0.f) : (float)x1[1];
                    ax += fmaxf(hx + (float)e1[0], 0.f);
                    ay += fmaxf(hy + (float)e1[1], 0.f);
                    hx = BN ? fmaxf((float)x2[0] * sc0 + sh0, 0.f) : (float)x2[0];
                    hy = BN ? fmaxf((float)x2[1] * sc1 + sh1, 0.f) : (float)x2[1];
                    ax += fmaxf(hx + (float)e2[0], 0.f);
                    ay += fmaxf(hy + (float)e2[1], 0.f);
                    hx = BN ? fmaxf((float)x3[0] * sc0 + sh0, 0.f) : (float)x3[0];
                    hy = BN ? fmaxf((float)x3[1] * sc1 + sh1, 0.f) : (float)x3[1];
                    ax += fmaxf(hx + (float)e3[0], 0.f);
                    ay += fmaxf(hy + (float)e3[1], 0.f);
                }
                for (; j < cnt; ++j) {
                    int s0 = __shfl(sv, j);
                    bf16x2 x0 = *(const bf16x2*)(xin + (long)s0 * 128 + lane * 2);
                    bf16x2 e0 = *(const bf16x2*)(e + (long)(base + j) * 128 + lane * 2);
                    float hx = BN ? fmaxf((float)x0[0] * sc0 + sh0, 0.f) : (float)x0[0];
                    float hy = BN ? fmaxf((float)x0[1] * sc1 + sh1, 0.f) : (float)x0[1];
                    ax += fmaxf(hx + (float)e0[0], 0.f);
                    ay += fmaxf(hy + (float)e0[1], 0.f);
                }
            }
        }
        bf16x2 o; o[0] = (bf16_t)ax; o[1] = (bf16_t)ay;
        *(bf16x2*)&T[r * S + lane * 2] = o;
    }
    __syncthreads();

    const int l16 = lane & 15, quad = lane >> 4;
    const int mbase = wv * 16 + quad * 4;

    f32x4 acc[8];
#pragma unroll
    for (int c = 0; c < 8; c++) acc[c] = (f32x4){0.f, 0.f, 0.f, 0.f};

#pragma unroll
    for (int kc = 0; kc < 4; ++kc) {
        bf16x8 af = *(const bf16x8*)&T[(wv * 16 + l16) * S + kc * 32 + quad * 8];
#pragma unroll
        for (int c = 0; c < 8; c++) {
            bf16x8 bfr = *(const bf16x8*)&Ws1[(((kc * 8 + c) * 64) + lane) * 8];
            acc[c] = MFMA16(af, bfr, acc[c]);
        }
    }
    __syncthreads();   // T becomes H

#pragma unroll
    for (int c = 0; c < 8; c++) {
        int col = c * 16 + l16;
        float bb = bls1[col];
#pragma unroll
        for (int q = 0; q < 4; q++)
            T[(mbase + q) * S + col] = (bf16_t)fmaxf(acc[c][q] + bb, 0.f);
    }
    __syncthreads();

#pragma unroll
    for (int c = 0; c < 8; c++) acc[c] = (f32x4){0.f, 0.f, 0.f, 0.f};

#pragma unroll
    for (int kc = 0; kc < 4; ++kc) {
        bf16x8 af = *(const bf16x8*)&T[(wv * 16 + l16) * S + kc * 32 + quad * 8];
#pragma unroll
        for (int c = 0; c < 8; c++) {
            bf16x8 bfr = *(const bf16x8*)&Ws2[(((kc * 8 + c) * 64) + lane) * 8];
            acc[c] = MFMA16(af, bfr, acc[c]);
        }
    }
    __syncthreads();   // T becomes Z

#pragma unroll
    for (int c = 0; c < 8; c++) {
        int col = c * 16 + l16;
        float bb = bls2[col];
        float s = 0.f, s2 = 0.f;
#pragma unroll
        for (int q = 0; q < 4; q++) {
            float v = acc[c][q] + bb;
            T[(mbase + q) * S + col] = (bf16_t)v;
            if (row0 + mbase + q < M) { s += v; s2 += v * v; }
        }
        s  += __shfl_xor(s, 16);  s  += __shfl_xor(s, 32);
        s2 += __shfl_xor(s2, 16); s2 += __shfl_xor(s2, 32);
        if (quad == 0) { atomicAdd(&bsum[col], s); atomicAdd(&bsq[col], s2); }
    }
    __syncthreads();

    for (int i = tid; i < 64 * 16; i += 256) {
        int row = i >> 4, seg = i & 15;
        long grow = row0 + row;
        if (grow < M)
            *(uint4*)&zout[grow * 128 + seg * 8] = *(const uint4*)&T[row * S + seg * 8];
    }
    if (tid < 128) {
        atomicAdd(&bn_sums[tid], bsum[tid]);
        atomicAdd(&bn_sums[128 + tid], bsq[tid]);
    }
}

// ---------------------------------------------------------------------------
__global__ void bn_fin_kernel(float* __restrict__ sums, const float* __restrict__ gamma,
                              const float* __restrict__ beta, float* __restrict__ scsh, int N)
{
    int c = threadIdx.x;
    float s  = sums[c];
    float sq = sums[128 + c];
    float mean = s / (float)N;
    float var  = sq / (float)N - mean * mean;
    float inv  = rsqrtf(var + 1e-5f);
    float sc   = gamma[c] * inv;
    scsh[c]       = sc;
    scsh[128 + c] = beta[c] - mean * sc;
    sums[c] = 0.f;
    sums[128 + c] = 0.f;
}

// ---------------------------------------------------------------------------
// Mean-pool over sorted batch, reading pre-BN z of the final layer.
// ---------------------------------------------------------------------------
__global__ __launch_bounds__(128) void pool_kernel(
    const bf16_t* __restrict__ z, const float* __restrict__ scsh,
    const int* __restrict__ batch,
    float* __restrict__ gsum, float* __restrict__ cnt, int N)
{
    int c = threadIdx.x;
    float sc = scsh[c], sh = scsh[128 + c];
    int n0 = blockIdx.x * 256;
    int n1 = min(n0 + 256, N);
    float acc = 0.f;
    int cur = -1, rc = 0;
    for (int n = n0; n < n1; ++n) {
        int g = batch[n];
        if (g != cur) {
            if (cur >= 0) {
                atomicAdd(&gsum[(long)cur * 128 + c], acc);
                if (c == 0) atomicAdd(&cnt[cur], (float)rc);
            }
            cur = g; acc = 0.f; rc = 0;
        }
        acc += fmaxf((float)z[(long)n * 128 + c] * sc + sh, 0.f);
        rc++;
    }
    if (cur >= 0) {
        atomicAdd(&gsum[(long)cur * 128 + c], acc);
        if (c == 0) atomicAdd(&cnt[cur], (float)rc);
    }
}

__global__ __launch_bounds__(128) void head_kernel(
    const float* __restrict__ gsum, const float* __restrict__ cnt,
    const float* __restrict__ ext_in,
    const float* __restrict__ ew1, const float* __restrict__ eb1,
    const float* __restrict__ ew2, const float* __restrict__ eb2,
    const float* __restrict__ rw1, const float* __restrict__ rb1,
    const float* __restrict__ rw2, const float* __restrict__ rb2,
    float* __restrict__ out)
{
    int g = blockIdx.x, c = threadIdx.x;
    __shared__ float sx[8];
    __shared__ float h1[128];
    __shared__ float comb[256];
    __shared__ float red[128];

    if (c < 8) sx[c] = ext_in[g * 8 + c];
    __syncthreads();
    float a = eb1[c];
#pragma unroll
    for (int k = 0; k < 8; k++) a += sx[k] * ew1[k * 128 + c];
    h1[c] = fmaxf(a, 0.f);
    __syncthreads();
    float b = eb2[c];
    for (int k = 0; k < 128; k++) b += h1[k] * ew2[k * 128 + c];
    comb[c]       = gsum[(long)g * 128 + c] / fmaxf(cnt[g], 1.0f);
    comb[128 + c] = b;
    __syncthreads();
    float r = rb1[c];
    for (int k = 0; k < 256; k++) r += comb[k] * rw1[k * 128 + c];
    r = fmaxf(r, 0.f);
    red[c] = r * rw2[c];
    __syncthreads();
    if (c == 0) {
        float s = rb2[0];
        for (int k = 0; k < 128; k++) s += red[k];
        out[g] = s;
    }
}

// ---------------------------------------------------------------------------
extern "C" void kernel_launch(void* const* d_in, const int* in_sizes, int n_in,
                              void* d_out, int out_size, void* d_ws, size_t ws_size,
                              hipStream_t stream)
{
    const float* x         = (const float*)d_in[0];
    const float* edge_attr = (const float*)d_in[1];
    const float* externals = (const float*)d_in[2];
    const float* node_w    = (const float*)d_in[3];
    const float* node_b    = (const float*)d_in[4];
    const float* ee_w1     = (const float*)d_in[5];
    const float* ee_b1     = (const float*)d_in[6];
    const float* ee_w2     = (const float*)d_in[7];
    const float* ee_b2     = (const float*)d_in[8];
    const float* conv_w1   = (const float*)d_in[9];
    const float* conv_b1   = (const float*)d_in[10];
    const float* conv_w2   = (const float*)d_in[11];
    const float* conv_b2   = (const float*)d_in[12];
    const float* bn_gamma  = (const float*)d_in[13];
    const float* bn_beta   = (const float*)d_in[14];
    const float* ext_w1    = (const float*)d_in[15];
    const float* ext_b1    = (const float*)d_in[16];
    const float* ext_w2    = (const float*)d_in[17];
    const float* ext_b2    = (const float*)d_in[18];
    const float* reg_w1    = (const float*)d_in[19];
    const float* reg_b1    = (const float*)d_in[20];
    const float* reg_w2    = (const float*)d_in[21];
    const float* reg_b2    = (const float*)d_in[22];
    const int* edge_index  = (const int*)d_in[23];
    const int* batch       = (const int*)d_in[24];

    const int N = in_sizes[0] / 32;
    const int E = in_sizes[1] / 16;
    const int G = in_sizes[2] / 8;
    const int NB = (N + 1023) / 1024;

    char* p = (char*)d_ws;
    auto alloc = [&](size_t bytes) -> void* {
        void* r = (void*)p;
        p += (bytes + 255) & ~(size_t)255;
        return r;
    };
    bf16_t* h       = (bf16_t*)alloc((size_t)N * 128 * 2);
    bf16_t* zA      = (bf16_t*)alloc((size_t)N * 128 * 2);
    bf16_t* zB      = (bf16_t*)alloc((size_t)N * 128 * 2);
    bf16_t* ebuf    = (bf16_t*)alloc((size_t)E * 128 * 2);   // dst-sorted
    int*    deg     = (int*)alloc((size_t)N * 4);
    int*    rowptr  = (int*)alloc(((size_t)N + 1) * 4);
    int*    cursor  = (int*)alloc((size_t)N * 4);
    int*    partials= (int*)alloc((size_t)N * 4);
    int*    bsums   = (int*)alloc((size_t)NB * 4);
    int*    boff    = (int*)alloc((size_t)NB * 4);
    int*    srcp    = (int*)alloc((size_t)E * 4);
    int*    eorig   = (int*)alloc((size_t)E * 4);
    bf16_t* node_wt = (bf16_t*)alloc(128 * 32 * 2);
    bf16_t* ee_w1t  = (bf16_t*)alloc(128 * 32 * 2);
    bf16_t* ee_w2t  = (bf16_t*)alloc(128 * 128 * 2);
    bf16_t* cw1t    = (bf16_t*)alloc(3 * 128 * 128 * 2);
    bf16_t* cw2t    = (bf16_t*)alloc(3 * 128 * 128 * 2);
    float*  bn_sums = (float*)alloc(256 * 4);
    float*  scsh    = (float*)alloc(256 * 4);
    float*  gsum    = (float*)alloc((size_t)G * 128 * 4);
    float*  cnt     = (float*)alloc((size_t)G * 4);

    // --- CSR build (by dst) ---
    hipMemsetAsync(deg, 0, (size_t)N * 4, stream);
    hipMemsetAsync(bn_sums, 0, 256 * 4, stream);
    hist_kernel<<<(E + 255) / 256, 256, 0, stream>>>(edge_index, deg, E);
    scanA_kernel<<<NB, 256, 0, stream>>>(deg, partials, bsums, N);
    scanB_kernel<<<1, 256, 0, stream>>>(bsums, boff, rowptr, NB, N);
    scanC_kernel<<<(N + 255) / 256, 256, 0, stream>>>(partials, boff, rowptr, cursor, N);
    scatter_kernel<<<(E + 255) / 256, 256, 0, stream>>>(edge_index, cursor, srcp, eorig, E);

    // --- weight prep ---
    prep_w_kernel<<<16, 256, 0, stream>>>(node_w, node_wt, 32, 32);
    prep_w_kernel<<<16, 256, 0, stream>>>(ee_w1, ee_w1t, 16, 32);
    prep_w_kernel<<<64, 256, 0, stream>>>(ee_w2, ee_w2t, 128, 128);
    for (int l = 0; l < 3; l++) {
        prep_w_kernel<<<64, 256, 0, stream>>>(conv_w1 + l * 16384, cw1t + l * 16384, 128, 128);
        prep_w_kernel<<<64, 256, 0, stream>>>(conv_w2 + l * 16384, cw2t + l * 16384, 128, 128);
    }

    // --- node encoder ---
    node_enc_kernel<<<(N + 127) / 128, 256, 0, stream>>>(x, N, node_wt, node_b, h);

    // --- edge encoder, CSR-order compute, sequential write ---
    edge_mlp_kernel<<<(E + 63) / 64, 256, 0, stream>>>(
        edge_attr, E, ee_w1t, ee_b1, ee_w2t, ee_b2, eorig, ebuf);

    // --- GINE layers: BN folded into the gather of the next consumer ---
    const int nblk = (N + 63) / 64;
    // layer 0: input h_enc (no BN), output zA
    aggr_conv_kernel<0><<<nblk, 256, 0, stream>>>(
        h, nullptr, ebuf, rowptr, srcp, N,
        cw1t + 0 * 16384, conv_b1 + 0 * 128, cw2t + 0 * 16384, conv_b2 + 0 * 128,
        zA, bn_sums);
    bn_fin_kernel<<<1, 128, 0, stream>>>(bn_sums, bn_gamma + 0 * 128, bn_beta + 0 * 128, scsh, N);
    // layer 1: input zA+scsh0, output zB
    aggr_conv_kernel<1><<<nblk, 256, 0, stream>>>(
        zA, scsh, ebuf, rowptr, srcp, N,
        cw1t + 1 * 16384, conv_b1 + 1 * 128, cw2t + 1 * 16384, conv_b2 + 1 * 128,
        zB, bn_sums);
    bn_fin_kernel<<<1, 128, 0, stream>>>(bn_sums, bn_gamma + 1 * 128, bn_beta + 1 * 128, scsh, N);
    // layer 2: input zB+scsh1, output zA
    aggr_conv_kernel<1><<<nblk, 256, 0, stream>>>(
        zB, scsh, ebuf, rowptr, srcp, N,
        cw1t + 2 * 16384, conv_b1 + 2 * 128, cw2t + 2 * 16384, conv_b2 + 2 * 128,
        zA, bn_sums);
    bn_fin_kernel<<<1, 128, 0, stream>>>(bn_sums, bn_gamma + 2 * 128, bn_beta + 2 * 128, scsh, N);

    // --- pooling (BN+relu applied on read) + head ---
    hipMemsetAsync(gsum, 0, (size_t)G * 128 * 4, stream);
    hipMemsetAsync(cnt, 0, (size_t)G * 4, stream);
    pool_kernel<<<(N + 255) / 256, 128, 0, stream>>>(zA, scsh, batch, gsum, cnt, N);
    head_kernel<<<G, 128, 0, stream>>>(gsum, cnt, externals,
                                       ext_w1, ext_b1, ext_w2, ext_b2,
                                       reg_w1, reg_b1, reg_w2, reg_b2,
                                       (float*)d_out);
}